// Round 5
// baseline (328.382 us; speedup 1.0000x reference)
//
#include <hip/hip_runtime.h>
#include <math.h>

// ReAttention round 5: R4 architecture with the k_sgen staging bug fixed
// (uint4 = 8 shorts, not 16 — K-tile was half-uninitialized -> NaN).
// B=8 N=1024 D=512 H=8 dh=64.
//
//  - conv bias cancels in train-mode BN (shifts mean only).
//  - attn'' = alpha_g*u_g + c_g ; u_g = sum_h conv_w[g,h]*S_h
//  - out_inner = alpha_g*O1 + c_g*vsum ; O1 = u @ v  (alpha-independent)
//  - S~ stored UNNORMALIZED bf16, head-interleaved: el ((b*N+n)*N+m)*8+h
//    so the mix reads 8 heads x 2 m in one 32B span.
//  - row sums accumulated to RSUM via atomics (2 m-half blocks); k_mixsv
//    computes rinv = 1/rsum inline.

#define Bz 8
#define Nn 1024
#define Dd 512
#define Hh 8
#define DH 64
#define INNER 512
#define QW 1536
#define SCALE 0.125f
#define BN_EPS 1e-5f

typedef short bf16x8 __attribute__((ext_vector_type(8)));
typedef float f32x4 __attribute__((ext_vector_type(4)));

#define MFMA(a, b, c) __builtin_amdgcn_mfma_f32_16x16x32_bf16((a), (b), (c), 0, 0, 0)

__device__ __forceinline__ unsigned short f2b(float f) {
  union { float f; unsigned u; } v; v.f = f;
  unsigned r = v.u + 0x7fffu + ((v.u >> 16) & 1u);
  return (unsigned short)(r >> 16);
}
__device__ __forceinline__ float b2f(unsigned short s) {
  union { unsigned u; float f; } v; v.u = ((unsigned)s) << 16;
  return v.f;
}

// ws layout (bytes)
#define WB_XB 0u                       // 8,388,608  x bf16
#define WB_QKV 8388608u                // 25,165,824 q,k bf16 (stride QW)
// O1A/O1B (fp32, 16,777,216 each) overlay XB+QKV after k_sgen is done
#define WB_O1A 0u
#define WB_O1B 16777216u
#define WB_VT 33554432u                // 8,388,608  v^T bf16 [b,g,d,m]
#define WB_SG 41943040u                // 134,217,728 S~ bf16 [b,n,m,h]
#define WB_O1BF WB_SG                  // 8,388,608 bf16, overlays dead S~
#define WB_WQT 176160768u              // 1,572,864
#define WB_WOT 177733632u              // 524,288
#define WB_RSUM 178257920u             // 262,144
#define WB_VSUM 178520064u             // 16,384
#define WB_STATS 178536448u            // 64
#define WB_AC 178536512u               // 64

// ---------------- x -> bf16 ------------------------------------------------
__global__ __launch_bounds__(256) void k_xbf(const float* __restrict__ X,
                                             unsigned short* __restrict__ XB) {
  const size_t i = ((size_t)blockIdx.x * 256 + threadIdx.x) * 8;
  float4 f0 = *(const float4*)(X + i);
  float4 f1 = *(const float4*)(X + i + 4);
  unsigned short o[8] = {f2b(f0.x), f2b(f0.y), f2b(f0.z), f2b(f0.w),
                         f2b(f1.x), f2b(f1.y), f2b(f1.z), f2b(f1.w)};
  *(uint4*)(XB + i) = *(uint4*)o;
}

// ---------------- transpose fp32 -> bf16: dst[C][R] = src[R][C]^T ----------
__global__ __launch_bounds__(256) void k_transpose(const float* __restrict__ src,
                                                   unsigned short* __restrict__ dst,
                                                   int R, int C) {
  __shared__ float tile[32][33];
  const int tc = blockIdx.x * 32, tr = blockIdx.y * 32;
  const int lx = threadIdx.x & 31, ly = threadIdx.x >> 5;
#pragma unroll
  for (int i = 0; i < 32; i += 8)
    tile[ly + i][lx] = src[(size_t)(tr + ly + i) * C + tc + lx];
  __syncthreads();
#pragma unroll
  for (int i = 0; i < 32; i += 8)
    dst[(size_t)(tc + ly + i) * R + tr + lx] = f2b(tile[lx][ly + i]);
}

// ---------------- K0: qkv = x @ w_qkv (bf16 MFMA) --------------------------
__global__ __launch_bounds__(256) void k_qkv(const unsigned short* __restrict__ XB,
                                             const unsigned short* __restrict__ WQT,
                                             unsigned short* __restrict__ qkv,
                                             unsigned short* __restrict__ vT) {
  extern __shared__ char smem[];
  unsigned short(*sA)[40] = (unsigned short(*)[40])smem;
  unsigned short(*sB)[40] = (unsigned short(*)[40])(smem + 128 * 40 * 2);
  unsigned short* sEp = (unsigned short*)smem;  // 128*136 after loop
  const int t = threadIdx.x;
  const int col0 = blockIdx.x * 128;
  const int row0 = blockIdx.y * 128;
  const bool isqk = (col0 < 2 * INNER);
  const int l = t & 63, w = t >> 6;
  const int wm = (w & 1) * 64, wn = (w >> 1) * 64;
  const int lm = l & 15, lq = l >> 4;
  const int srow = t >> 1, skc = (t & 1) * 16;
  f32x4 acc[4][4] = {};
  for (int k0 = 0; k0 < Dd; k0 += 32) {
    {
      const unsigned short* src = XB + (size_t)(row0 + srow) * Dd + k0 + skc;
      *(uint4*)&sA[srow][skc] = *(const uint4*)src;
      *(uint4*)&sA[srow][skc + 8] = *(const uint4*)(src + 8);
    }
    {
      const unsigned short* srcB = WQT + (size_t)(col0 + srow) * Dd + k0 + skc;
      *(uint4*)&sB[srow][skc] = *(const uint4*)srcB;
      *(uint4*)&sB[srow][skc + 8] = *(const uint4*)(srcB + 8);
    }
    __syncthreads();
    bf16x8 af[4], bfr[4];
#pragma unroll
    for (int i = 0; i < 4; i++) af[i] = *(const bf16x8*)&sA[wm + 16 * i + lm][lq * 8];
#pragma unroll
    for (int j = 0; j < 4; j++) bfr[j] = *(const bf16x8*)&sB[wn + 16 * j + lm][lq * 8];
    if (isqk) {
#pragma unroll
      for (int i = 0; i < 4; i++)
#pragma unroll
        for (int j = 0; j < 4; j++) acc[i][j] = MFMA(bfr[i], af[j], acc[i][j]);
    } else {
#pragma unroll
      for (int i = 0; i < 4; i++)
#pragma unroll
        for (int j = 0; j < 4; j++) acc[i][j] = MFMA(af[i], bfr[j], acc[i][j]);
    }
    __syncthreads();
  }
  if (isqk) {
#pragma unroll
    for (int jc = 0; jc < 4; jc++)
#pragma unroll
      for (int ir = 0; ir < 4; ir++) {
        unsigned short us[4];
#pragma unroll
        for (int r = 0; r < 4; r++) us[r] = f2b(acc[jc][ir][r]);
        *(uint2*)&sEp[(wm + 16 * ir + lm) * 136 + wn + 16 * jc + 4 * lq] = *(uint2*)us;
      }
    __syncthreads();
    const int row = t >> 1, half = t & 1;
    const unsigned short* src = &sEp[row * 136 + half * 64];
    unsigned short* dst = qkv + (size_t)(row0 + row) * QW + col0 + half * 64;
#pragma unroll
    for (int c = 0; c < 8; c++) *(uint4*)(dst + c * 8) = *(const uint4*)(src + c * 8);
  } else {
#pragma unroll
    for (int ir = 0; ir < 4; ir++)
#pragma unroll
      for (int jc = 0; jc < 4; jc++) {
        unsigned short us[4];
#pragma unroll
        for (int r = 0; r < 4; r++) us[r] = f2b(acc[ir][jc][r]);
        *(uint2*)&sEp[(wn + 16 * jc + lm) * 136 + wm + 16 * ir + 4 * lq] = *(uint2*)us;
      }
    __syncthreads();
    const int row = t >> 1, half = t & 1;
    const int gd = col0 - 2 * INNER + row;
    const int bq = row0 >> 10, mseq0 = row0 & 1023;
    const unsigned short* src = &sEp[row * 136 + half * 64];
    unsigned short* dst =
        vT + (((size_t)(bq * Hh + (gd >> 6)) * DH + (gd & 63)) << 10) + mseq0 + half * 64;
#pragma unroll
    for (int c = 0; c < 8; c++) *(uint4*)(dst + c * 8) = *(const uint4*)(src + c * 8);
  }
}

// ---------------- k_vsum --------------------------------------------------
__global__ __launch_bounds__(256) void k_vsum(const unsigned short* __restrict__ vT,
                                              float* __restrict__ vsum) {
  const int bg = blockIdx.x;
  const int d = threadIdx.x >> 2, qq = threadIdx.x & 3;
  __shared__ float red[64][4];
  const unsigned short* p = vT + ((size_t)bg * DH + d) * Nn + qq * 256;
  float s = 0.f;
  for (int m = 0; m < 256; m += 4) {
    uint2 rr = *(const uint2*)(p + m);
    s += b2f((unsigned short)(rr.x & 0xffff)) + b2f((unsigned short)(rr.x >> 16)) +
         b2f((unsigned short)(rr.y & 0xffff)) + b2f((unsigned short)(rr.y >> 16));
  }
  red[d][qq] = s;
  __syncthreads();
  if (threadIdx.x < 64)
    vsum[(size_t)bg * DH + threadIdx.x] =
        red[threadIdx.x][0] + red[threadIdx.x][1] + red[threadIdx.x][2] + red[threadIdx.x][3];
}

// ---------------- kA: S~ head-interleaved + row-sum partials ---------------
// grid (b=8, nt=32, mh=2); block 512 = 8 waves, wave w = head w, n-tile 32.
__global__ __launch_bounds__(512, 4) void k_sgen(const unsigned short* __restrict__ qkv,
                                                 unsigned short* __restrict__ Sg,
                                                 float* __restrict__ rsum) {
  __shared__ unsigned short sK[8 * 32 * 72];  // 36,864 B
  __shared__ unsigned short sT[32 * 264];     // 16,896 B  [n][m*8+h], pad 8
  const int b = blockIdx.x;
  const int n0 = blockIdx.y * 32;
  const int mh = blockIdx.z;
  const int t = threadIdx.x;
  const int w = t >> 6, l = t & 63;
  const int lm = l & 15, lq = l >> 4;
  // Q frags for head w, rows n0+16i+lm, held across m loop
  bf16x8 qf[2][2];
#pragma unroll
  for (int i = 0; i < 2; i++) {
    const unsigned short* qp =
        qkv + (size_t)(b * Nn + n0 + 16 * i + lm) * QW + w * DH + lq * 8;
    qf[i][0] = *(const bf16x8*)qp;
    qf[i][1] = *(const bf16x8*)(qp + 32);
  }
  float psum[2] = {0.f, 0.f};
  for (int it = 0; it < 16; it++) {
    const int m0 = mh * 512 + it * 32;
    {  // stage K: all heads, 32m x 64d, [h][m][72]. uint4 = 8 shorts;
       // 2048 uint4 total = 512 thr x 4; 8 consecutive thr = one 128B row.
#pragma unroll
      for (int s = 0; s < 4; s++) {
        const int c = t + s * 512;
        const int hh = c >> 8, mm = (c >> 3) & 31, qq = c & 7;
        *(uint4*)&sK[(hh * 32 + mm) * 72 + qq * 8] = *(const uint4*)(
            qkv + (size_t)(b * Nn + m0 + mm) * QW + INNER + hh * DH + qq * 8);
      }
    }
    __syncthreads();  // sK ready; prev coop-store readers of sT done
    f32x4 lac[2][2] = {};
#pragma unroll
    for (int jm = 0; jm < 2; jm++) {
      bf16x8 ka0 = *(const bf16x8*)&sK[(w * 32 + 16 * jm + lm) * 72 + lq * 8];
      bf16x8 ka1 = *(const bf16x8*)&sK[(w * 32 + 16 * jm + lm) * 72 + 32 + lq * 8];
#pragma unroll
      for (int i = 0; i < 2; i++) {
        lac[i][jm] = MFMA(ka0, qf[i][0], lac[i][jm]);
        lac[i][jm] = MFMA(ka1, qf[i][1], lac[i][jm]);
      }
    }
#pragma unroll
    for (int i = 0; i < 2; i++)
#pragma unroll
      for (int jm = 0; jm < 2; jm++)
#pragma unroll
        for (int r = 0; r < 4; r++) {
          float e = __expf(lac[i][jm][r] * SCALE);
          psum[i] += e;
          sT[(16 * i + lm) * 264 + (16 * jm + 4 * lq + r) * 8 + w] = f2b(e);
        }
    __syncthreads();  // sT complete; sK consumers done
    {  // coop store: 32 rows x 512B, fully coalesced
      const int row = t >> 4, ck = t & 15;
      unsigned short* dst =
          Sg + (((size_t)(b * Nn + n0 + row) << 10) + m0) * 8 + ck * 16;
      const unsigned short* src = &sT[row * 264 + ck * 16];
      *(uint4*)dst = *(const uint4*)src;
      *(uint4*)(dst + 8) = *(const uint4*)(src + 8);
    }
  }
#pragma unroll
  for (int i = 0; i < 2; i++) {
    psum[i] += __shfl_xor(psum[i], 16);
    psum[i] += __shfl_xor(psum[i], 32);
  }
  if (lq == 0) {
    atomicAdd(&rsum[(size_t)(b * Hh + w) * Nn + n0 + lm], psum[0]);
    atomicAdd(&rsum[(size_t)(b * Hh + w) * Nn + n0 + 16 + lm], psum[1]);
  }
}

// ---------------- kB: mix + stats + S@V, prefetched, 1 barrier/iter --------
// grid (b=8, nt=64, mh=2); block 512 = 8 waves; wave w = group g.
__global__ __launch_bounds__(512, 4) void k_mixsv(const unsigned short* __restrict__ Sg,
                                                  const unsigned short* __restrict__ vT,
                                                  const float* __restrict__ rsum,
                                                  const float* __restrict__ conv_w,
                                                  float* __restrict__ O1A,
                                                  float* __restrict__ O1B,
                                                  float* __restrict__ stats) {
  __shared__ unsigned short sU[2][8][16][68];  // 34,816 B double-buffered
  __shared__ float sRed[8][16];
  const int b = blockIdx.x;
  const int n0 = blockIdx.y * 16;
  const int mbase = blockIdx.z * 512;
  float* __restrict__ O1 = blockIdx.z ? O1B : O1A;
  const int t = threadIdx.x;
  const int w = t >> 6, l = t & 63;
  const int lm = l & 15, lq = l >> 4;
  const int mxn = t >> 5, mxm = (t & 31) * 2;
  float cw[64];
#pragma unroll
  for (int i = 0; i < 64; i++) cw[i] = conv_w[i];  // uniform -> SGPRs
  float rv[8];
#pragma unroll
  for (int h = 0; h < 8; h++) rv[h] = 1.0f / rsum[(size_t)(b * Hh + h) * Nn + n0 + mxn];
  const unsigned short* sN = Sg + ((size_t)(b * Nn + n0 + mxn) << 13);  // *1024*8
  f32x4 oacc[4] = {};
  float su[8] = {}, su2[8] = {};
  uint4 sreg[2][2];
  {
    const unsigned short* p = sN + ((size_t)(mbase + mxm) << 3);
    sreg[0][0] = *(const uint4*)p;
    sreg[0][1] = *(const uint4*)(p + 8);
  }
#pragma unroll
  for (int it = 0; it < 8; it++) {
    const int cur = it & 1, nxt = cur ^ 1;
    if (it < 7) {  // prefetch next iter's S across the barrier
      const unsigned short* p = sN + ((size_t)(mbase + (it + 1) * 64 + mxm) << 3);
      sreg[nxt][0] = *(const uint4*)p;
      sreg[nxt][1] = *(const uint4*)(p + 8);
    }
    {  // mix from sreg[cur]: 2 m-positions x 8 heads
      float sx[8], sy[8];
      const unsigned* pe = (const unsigned*)&sreg[cur][0];  // h0..7 (m even)
      const unsigned* po = (const unsigned*)&sreg[cur][1];  // h0..7 (m odd)
#pragma unroll
      for (int h = 0; h < 4; h++) {
        sx[2 * h] = b2f((unsigned short)(pe[h] & 0xffff)) * rv[2 * h];
        sx[2 * h + 1] = b2f((unsigned short)(pe[h] >> 16)) * rv[2 * h + 1];
        sy[2 * h] = b2f((unsigned short)(po[h] & 0xffff)) * rv[2 * h];
        sy[2 * h + 1] = b2f((unsigned short)(po[h] >> 16)) * rv[2 * h + 1];
      }
#pragma unroll
      for (int g = 0; g < 8; g++) {
        float u0 = 0.f, u1 = 0.f;
#pragma unroll
        for (int h = 0; h < 8; h++) {
          u0 += cw[g * 8 + h] * sx[h];
          u1 += cw[g * 8 + h] * sy[h];
        }
        su[g] += u0 + u1;
        su2[g] += u0 * u0 + u1 * u1;
        *(unsigned*)&sU[cur][g][mxn][mxm] = (unsigned)f2b(u0) | ((unsigned)f2b(u1) << 16);
      }
    }
    __syncthreads();  // sU[cur] ready (and prev iter's PV readers are past)
    {  // S@V for group w: A = sU[cur][w], B = vT direct from global (L2-hot)
      bf16x8 uf0 = *(const bf16x8*)&sU[cur][w][lm][lq * 8];
      bf16x8 uf1 = *(const bf16x8*)&sU[cur][w][lm][32 + lq * 8];
#pragma unroll
      for (int j = 0; j < 4; j++) {
        const unsigned short* vp =
            vT + (((size_t)(b * Hh + w) * DH + 16 * j + lm) << 10) + mbase + it * 64 + lq * 8;
        bf16x8 v0 = *(const bf16x8*)vp;
        bf16x8 v1 = *(const bf16x8*)(vp + 32);
        oacc[j] = MFMA(uf0, v0, oacc[j]);
        oacc[j] = MFMA(uf1, v1, oacc[j]);
      }
    }
  }
#pragma unroll
  for (int j = 0; j < 4; j++)
#pragma unroll
    for (int r = 0; r < 4; r++)
      O1[((size_t)(b * Hh + w) * Nn + n0 + lq * 4 + r) * DH + 16 * j + lm] = oacc[j][r];
#pragma unroll
  for (int g = 0; g < 8; g++) {
    float a = su[g], q = su2[g];
    for (int off = 32; off; off >>= 1) {
      a += __shfl_down(a, off);
      q += __shfl_down(q, off);
    }
    if (l == 0) {
      sRed[w][g] = a;
      sRed[w][8 + g] = q;
    }
  }
  __syncthreads();
  if (t < 16) {
    float s = 0.f;
#pragma unroll
    for (int ww = 0; ww < 8; ww++) s += sRed[ww][t];
    atomicAdd(&stats[t], s);
  }
}

// ---------------- K3: alpha/const ------------------------------------------
__global__ void k_alpha(const float* __restrict__ stats, const float* __restrict__ bn_gamma,
                        const float* __restrict__ bn_beta, float* __restrict__ ac) {
  const int g = threadIdx.x;
  if (g < 8) {
    const float cnt = (float)Bz * (float)Nn * (float)Nn;
    float Eu = stats[g] / cnt;
    float Eu2 = stats[8 + g] / cnt;
    float inv = rsqrtf(Eu2 - Eu * Eu + BN_EPS);
    float alpha = bn_gamma[g] * inv;
    ac[g] = alpha;
    ac[8 + g] = bn_beta[g] - Eu * alpha;
  }
}

// ---------------- k_o1aff: O1bf = bf16(alpha*(O1A+O1B) + c*vsum) -----------
__global__ __launch_bounds__(256) void k_o1aff(const float* __restrict__ O1A,
                                               const float* __restrict__ O1B,
                                               const float* __restrict__ vsum,
                                               const float* __restrict__ ac,
                                               unsigned short* __restrict__ O1BF) {
  const size_t i4 = ((size_t)blockIdx.x * 256 + threadIdx.x) * 4;
  const int bg = (int)(i4 >> 16);
  const int g = bg & 7;
  const int d = (int)(i4 & 63);
  float4 a = *(const float4*)(O1A + i4);
  float4 bb = *(const float4*)(O1B + i4);
  float4 v = *(const float4*)(vsum + (size_t)bg * DH + d);
  const float al = ac[g], cc = ac[8 + g];
  unsigned short o[4] = {f2b(al * (a.x + bb.x) + cc * v.x), f2b(al * (a.y + bb.y) + cc * v.y),
                         f2b(al * (a.z + bb.z) + cc * v.z), f2b(al * (a.w + bb.w) + cc * v.w)};
  *(uint2*)(O1BF + i4) = *(uint2*)o;
}

// ---------------- K4: out = O1bf @ w_out + b_out (pure bf16 MFMA) ----------
__global__ __launch_bounds__(256) void k_out(const unsigned short* __restrict__ O1BF,
                                             const unsigned short* __restrict__ WOT,
                                             const float* __restrict__ bout,
                                             float* __restrict__ out) {
  __shared__ unsigned short sA[128][40];
  __shared__ unsigned short sB[128][40];
  const int t = threadIdx.x;
  const int col0 = blockIdx.x * 128, row0 = blockIdx.y * 128;
  const int l = t & 63, w = t >> 6;
  const int wm = (w & 1) * 64, wn = (w >> 1) * 64;
  const int lm = l & 15, lq = l >> 4;
  const int srow = t >> 1, skc = (t & 1) * 16;
  const int b = row0 >> 10;
  const int nn = (row0 + srow) & 1023;
  f32x4 acc[4][4] = {};
  for (int k0 = 0; k0 < INNER; k0 += 32) {
    {
      const int k = k0 + skc;
      const int g = k >> 6, dd = k & 63;
      const unsigned short* src = O1BF + ((size_t)(b * Hh + g) * Nn + nn) * DH + dd;
      *(uint4*)&sA[srow][skc] = *(const uint4*)src;
      *(uint4*)&sA[srow][skc + 8] = *(const uint4*)(src + 8);
    }
    {
      const unsigned short* srcB = WOT + (size_t)(col0 + srow) * INNER + k0 + skc;
      *(uint4*)&sB[srow][skc] = *(const uint4*)srcB;
      *(uint4*)&sB[srow][skc + 8] = *(const uint4*)(srcB + 8);
    }
    __syncthreads();
    bf16x8 af[4], bfr[4];
#pragma unroll
    for (int i = 0; i < 4; i++) af[i] = *(const bf16x8*)&sA[wm + 16 * i + lm][lq * 8];
#pragma unroll
    for (int j = 0; j < 4; j++) bfr[j] = *(const bf16x8*)&sB[wn + 16 * j + lm][lq * 8];
#pragma unroll
    for (int i = 0; i < 4; i++)
#pragma unroll
      for (int j = 0; j < 4; j++) acc[i][j] = MFMA(af[i], bfr[j], acc[i][j]);
    __syncthreads();
  }
#pragma unroll
  for (int j = 0; j < 4; j++) {
    const int col = col0 + wn + 16 * j + lm;
    const float bo = bout[col];
#pragma unroll
    for (int i = 0; i < 4; i++) {
      const int rbase = row0 + wm + 16 * i + lq * 4;
#pragma unroll
      for (int r = 0; r < 4; r++) out[(size_t)(rbase + r) * Dd + col] = acc[i][j][r] + bo;
    }
  }
}

extern "C" void kernel_launch(void* const* d_in, const int* in_sizes, int n_in,
                              void* d_out, int out_size, void* d_ws, size_t ws_size,
                              hipStream_t stream) {
  const float* x = (const float*)d_in[0];
  const float* w_qkv = (const float*)d_in[1];
  const float* conv_w = (const float*)d_in[2];
  // d_in[3] = conv_b : cancels in train-mode BN.
  const float* bn_gamma = (const float*)d_in[4];
  const float* bn_beta = (const float*)d_in[5];
  const float* w_out = (const float*)d_in[6];
  const float* b_out = (const float*)d_in[7];
  char* ws = (char*)d_ws;
  unsigned short* XB = (unsigned short*)(ws + WB_XB);
  unsigned short* QKV = (unsigned short*)(ws + WB_QKV);
  unsigned short* VT = (unsigned short*)(ws + WB_VT);
  unsigned short* SG = (unsigned short*)(ws + WB_SG);
  unsigned short* WQT = (unsigned short*)(ws + WB_WQT);
  unsigned short* WOT = (unsigned short*)(ws + WB_WOT);
  float* O1Ap = (float*)(ws + WB_O1A);
  float* O1Bp = (float*)(ws + WB_O1B);
  unsigned short* O1BF = (unsigned short*)(ws + WB_O1BF);
  float* RSUM = (float*)(ws + WB_RSUM);
  float* VSUM = (float*)(ws + WB_VSUM);
  float* STATS = (float*)(ws + WB_STATS);
  float* AC = (float*)(ws + WB_AC);

  hipMemsetAsync(STATS, 0, 64, stream);
  hipMemsetAsync(RSUM, 0, 262144, stream);
  k_xbf<<<2048, 256, 0, stream>>>(x, XB);
  k_transpose<<<dim3(48, 16), 256, 0, stream>>>(w_qkv, WQT, 512, 1536);
  k_transpose<<<dim3(16, 16), 256, 0, stream>>>(w_out, WOT, 512, 512);
  k_qkv<<<dim3(12, 64), 256, 34816, stream>>>(XB, WQT, QKV, VT);
  k_vsum<<<64, 256, 0, stream>>>(VT, VSUM);
  k_sgen<<<dim3(8, 32, 2), 512, 0, stream>>>(QKV, SG, RSUM);
  k_mixsv<<<dim3(8, 64, 2), 512, 0, stream>>>(SG, VT, RSUM, conv_w, O1Ap, O1Bp, STATS);
  k_alpha<<<1, 64, 0, stream>>>(STATS, bn_gamma, bn_beta, AC);
  k_o1aff<<<4096, 256, 0, stream>>>(O1Ap, O1Bp, VSUM, AC, O1BF);
  k_out<<<dim3(4, 64), 256, 0, stream>>>(O1BF, WOT, b_out, (float*)d_out);
}

// Round 6
// 271.670 us; speedup vs baseline: 1.2088x; 1.2088x over previous
//
#include <hip/hip_runtime.h>
#include <math.h>

// ReAttention round 6: de-spilled k_mixsv (single-z, launch_bounds(512,2),
// single sU buffer) + full fp16 pipeline (fp32 accum/stats).
// B=8 N=1024 D=512 H=8 dh=64.
//
//  - conv bias cancels in train-mode BN (shifts mean only).
//  - attn'' = alpha_g*u_g + c_g ; u_g = sum_h conv_w[g,h]*S_h
//  - out_inner = alpha_g*O1 + c_g*vsum ; O1 = u @ v  (alpha-independent)
//  - S~ stored UNNORMALIZED fp16, head-interleaved: el ((b*N+n)*N+m)*8+h
//    (mix reads 8 heads x 2 m as two contiguous uint4).
//  - R5 lesson: WRITE_SIZE 210 MB vs 33 MB expected = scratch spill from
//    reg prefetch + (512,4) VGPR cap. Keep live set small, cap at 256.

#define Bz 8
#define Nn 1024
#define Dd 512
#define Hh 8
#define DH 64
#define INNER 512
#define QW 1536
#define SCALE 0.125f
#define BN_EPS 1e-5f

typedef _Float16 __f16;
typedef __f16 f16x8 __attribute__((ext_vector_type(8)));
typedef float f32x4 __attribute__((ext_vector_type(4)));

#define MFMA16(a, b, c) __builtin_amdgcn_mfma_f32_16x16x32_f16((a), (b), (c), 0, 0, 0)

__device__ __forceinline__ unsigned short f2h(float f) {
  union { __f16 h; unsigned short s; } v;
  v.h = (__f16)f;  // v_cvt_f16_f32, RTN
  return v.s;
}
__device__ __forceinline__ float h2f(unsigned short s) {
  union { unsigned short s; __f16 h; } v;
  v.s = s;
  return (float)v.h;
}

// ws layout (bytes)
#define WB_XB 0u                       // 8,388,608  x fp16
#define WB_QKV 8388608u                // 25,165,824 q,k fp16 (stride QW)
#define WB_O1 0u                       // 16,777,216 fp32 (overlays XB + head of QKV; both dead)
#define WB_VT 33554432u                // 8,388,608  v^T fp16 [b,g,d,m]
#define WB_SG 41943040u                // 134,217,728 S~ fp16 [b,n,m,h]
#define WB_O1BF WB_SG                  // 8,388,608 fp16, overlays dead S~
#define WB_WQT 176160768u              // 1,572,864
#define WB_WOT 177733632u              // 524,288
#define WB_RSUM 178257920u             // 262,144
#define WB_VSUM 178520064u             // 16,384
#define WB_STATS 178536448u            // 64
#define WB_AC 178536512u               // 64

// ---------------- x -> fp16 ------------------------------------------------
__global__ __launch_bounds__(256) void k_xbf(const float* __restrict__ X,
                                             unsigned short* __restrict__ XB) {
  const size_t i = ((size_t)blockIdx.x * 256 + threadIdx.x) * 8;
  float4 f0 = *(const float4*)(X + i);
  float4 f1 = *(const float4*)(X + i + 4);
  unsigned short o[8] = {f2h(f0.x), f2h(f0.y), f2h(f0.z), f2h(f0.w),
                         f2h(f1.x), f2h(f1.y), f2h(f1.z), f2h(f1.w)};
  *(uint4*)(XB + i) = *(uint4*)o;
}

// ---------------- transpose fp32 -> fp16: dst[C][R] = src[R][C]^T ----------
__global__ __launch_bounds__(256) void k_transpose(const float* __restrict__ src,
                                                   unsigned short* __restrict__ dst,
                                                   int R, int C) {
  __shared__ float tile[32][33];
  const int tc = blockIdx.x * 32, tr = blockIdx.y * 32;
  const int lx = threadIdx.x & 31, ly = threadIdx.x >> 5;
#pragma unroll
  for (int i = 0; i < 32; i += 8)
    tile[ly + i][lx] = src[(size_t)(tr + ly + i) * C + tc + lx];
  __syncthreads();
#pragma unroll
  for (int i = 0; i < 32; i += 8)
    dst[(size_t)(tc + ly + i) * R + tr + lx] = f2h(tile[lx][ly + i]);
}

// ---------------- K0: qkv = x @ w_qkv (fp16 MFMA) --------------------------
__global__ __launch_bounds__(256) void k_qkv(const unsigned short* __restrict__ XB,
                                             const unsigned short* __restrict__ WQT,
                                             unsigned short* __restrict__ qkv,
                                             unsigned short* __restrict__ vT) {
  extern __shared__ char smem[];
  unsigned short(*sA)[40] = (unsigned short(*)[40])smem;
  unsigned short(*sB)[40] = (unsigned short(*)[40])(smem + 128 * 40 * 2);
  unsigned short* sEp = (unsigned short*)smem;  // 128*136 after loop
  const int t = threadIdx.x;
  const int col0 = blockIdx.x * 128;
  const int row0 = blockIdx.y * 128;
  const bool isqk = (col0 < 2 * INNER);
  const int l = t & 63, w = t >> 6;
  const int wm = (w & 1) * 64, wn = (w >> 1) * 64;
  const int lm = l & 15, lq = l >> 4;
  const int srow = t >> 1, skc = (t & 1) * 16;
  f32x4 acc[4][4] = {};
  for (int k0 = 0; k0 < Dd; k0 += 32) {
    {
      const unsigned short* src = XB + (size_t)(row0 + srow) * Dd + k0 + skc;
      *(uint4*)&sA[srow][skc] = *(const uint4*)src;
      *(uint4*)&sA[srow][skc + 8] = *(const uint4*)(src + 8);
    }
    {
      const unsigned short* srcB = WQT + (size_t)(col0 + srow) * Dd + k0 + skc;
      *(uint4*)&sB[srow][skc] = *(const uint4*)srcB;
      *(uint4*)&sB[srow][skc + 8] = *(const uint4*)(srcB + 8);
    }
    __syncthreads();
    f16x8 af[4], bfr[4];
#pragma unroll
    for (int i = 0; i < 4; i++) af[i] = *(const f16x8*)&sA[wm + 16 * i + lm][lq * 8];
#pragma unroll
    for (int j = 0; j < 4; j++) bfr[j] = *(const f16x8*)&sB[wn + 16 * j + lm][lq * 8];
    if (isqk) {
#pragma unroll
      for (int i = 0; i < 4; i++)
#pragma unroll
        for (int j = 0; j < 4; j++) acc[i][j] = MFMA16(bfr[i], af[j], acc[i][j]);
    } else {
#pragma unroll
      for (int i = 0; i < 4; i++)
#pragma unroll
        for (int j = 0; j < 4; j++) acc[i][j] = MFMA16(af[i], bfr[j], acc[i][j]);
    }
    __syncthreads();
  }
  if (isqk) {
#pragma unroll
    for (int jc = 0; jc < 4; jc++)
#pragma unroll
      for (int ir = 0; ir < 4; ir++) {
        unsigned short us[4];
#pragma unroll
        for (int r = 0; r < 4; r++) us[r] = f2h(acc[jc][ir][r]);
        *(uint2*)&sEp[(wm + 16 * ir + lm) * 136 + wn + 16 * jc + 4 * lq] = *(uint2*)us;
      }
    __syncthreads();
    const int row = t >> 1, half = t & 1;
    const unsigned short* src = &sEp[row * 136 + half * 64];
    unsigned short* dst = qkv + (size_t)(row0 + row) * QW + col0 + half * 64;
#pragma unroll
    for (int c = 0; c < 8; c++) *(uint4*)(dst + c * 8) = *(const uint4*)(src + c * 8);
  } else {
#pragma unroll
    for (int ir = 0; ir < 4; ir++)
#pragma unroll
      for (int jc = 0; jc < 4; jc++) {
        unsigned short us[4];
#pragma unroll
        for (int r = 0; r < 4; r++) us[r] = f2h(acc[ir][jc][r]);
        *(uint2*)&sEp[(wn + 16 * jc + lm) * 136 + wm + 16 * ir + 4 * lq] = *(uint2*)us;
      }
    __syncthreads();
    const int row = t >> 1, half = t & 1;
    const int gd = col0 - 2 * INNER + row;
    const int bq = row0 >> 10, mseq0 = row0 & 1023;
    const unsigned short* src = &sEp[row * 136 + half * 64];
    unsigned short* dst =
        vT + (((size_t)(bq * Hh + (gd >> 6)) * DH + (gd & 63)) << 10) + mseq0 + half * 64;
#pragma unroll
    for (int c = 0; c < 8; c++) *(uint4*)(dst + c * 8) = *(const uint4*)(src + c * 8);
  }
}

// ---------------- k_vsum --------------------------------------------------
__global__ __launch_bounds__(256) void k_vsum(const unsigned short* __restrict__ vT,
                                              float* __restrict__ vsum) {
  const int bg = blockIdx.x;
  const int d = threadIdx.x >> 2, qq = threadIdx.x & 3;
  __shared__ float red[64][4];
  const unsigned short* p = vT + ((size_t)bg * DH + d) * Nn + qq * 256;
  float s = 0.f;
  for (int m = 0; m < 256; m += 4) {
    uint2 rr = *(const uint2*)(p + m);
    s += h2f((unsigned short)(rr.x & 0xffff)) + h2f((unsigned short)(rr.x >> 16)) +
         h2f((unsigned short)(rr.y & 0xffff)) + h2f((unsigned short)(rr.y >> 16));
  }
  red[d][qq] = s;
  __syncthreads();
  if (threadIdx.x < 64)
    vsum[(size_t)bg * DH + threadIdx.x] =
        red[threadIdx.x][0] + red[threadIdx.x][1] + red[threadIdx.x][2] + red[threadIdx.x][3];
}

// ---------------- kA: S~ head-interleaved + row-sum partials ---------------
// grid (b=8, nt=32, mh=2); block 512 = 8 waves, wave w = head w.
__global__ __launch_bounds__(512, 2) void k_sgen(const unsigned short* __restrict__ qkv,
                                                 unsigned short* __restrict__ Sg,
                                                 float* __restrict__ rsum) {
  __shared__ unsigned short sK[8 * 32 * 72];  // 36,864 B
  __shared__ unsigned short sT[32 * 264];     // 16,896 B  [n][m*8+h], pad 8
  const int b = blockIdx.x;
  const int n0 = blockIdx.y * 32;
  const int mh = blockIdx.z;
  const int t = threadIdx.x;
  const int w = t >> 6, l = t & 63;
  const int lm = l & 15, lq = l >> 4;
  f16x8 qf[2][2];
#pragma unroll
  for (int i = 0; i < 2; i++) {
    const unsigned short* qp =
        qkv + (size_t)(b * Nn + n0 + 16 * i + lm) * QW + w * DH + lq * 8;
    qf[i][0] = *(const f16x8*)qp;
    qf[i][1] = *(const f16x8*)(qp + 32);
  }
  float psum[2] = {0.f, 0.f};
  for (int it = 0; it < 16; it++) {
    const int m0 = mh * 512 + it * 32;
    {  // stage K: all heads, 32m x 64d, [h][m][72]; uint4 = 8 shorts
#pragma unroll
      for (int s = 0; s < 4; s++) {
        const int c = t + s * 512;
        const int hh = c >> 8, mm = (c >> 3) & 31, qq = c & 7;
        *(uint4*)&sK[(hh * 32 + mm) * 72 + qq * 8] = *(const uint4*)(
            qkv + (size_t)(b * Nn + m0 + mm) * QW + INNER + hh * DH + qq * 8);
      }
    }
    __syncthreads();
    f32x4 lac[2][2] = {};
#pragma unroll
    for (int jm = 0; jm < 2; jm++) {
      f16x8 ka0 = *(const f16x8*)&sK[(w * 32 + 16 * jm + lm) * 72 + lq * 8];
      f16x8 ka1 = *(const f16x8*)&sK[(w * 32 + 16 * jm + lm) * 72 + 32 + lq * 8];
#pragma unroll
      for (int i = 0; i < 2; i++) {
        lac[i][jm] = MFMA16(ka0, qf[i][0], lac[i][jm]);
        lac[i][jm] = MFMA16(ka1, qf[i][1], lac[i][jm]);
      }
    }
#pragma unroll
    for (int i = 0; i < 2; i++)
#pragma unroll
      for (int jm = 0; jm < 2; jm++)
#pragma unroll
        for (int r = 0; r < 4; r++) {
          float e = __expf(lac[i][jm][r] * SCALE);
          psum[i] += e;
          sT[(16 * i + lm) * 264 + (16 * jm + 4 * lq + r) * 8 + w] = f2h(e);
        }
    __syncthreads();
    {  // coop store: 32 rows x 512B, fully coalesced
      const int row = t >> 4, ck = t & 15;
      unsigned short* dst =
          Sg + (((size_t)(b * Nn + n0 + row) << 10) + m0) * 8 + ck * 16;
      const unsigned short* src = &sT[row * 264 + ck * 16];
      *(uint4*)dst = *(const uint4*)src;
      *(uint4*)(dst + 8) = *(const uint4*)(src + 8);
    }
  }
#pragma unroll
  for (int i = 0; i < 2; i++) {
    psum[i] += __shfl_xor(psum[i], 16);
    psum[i] += __shfl_xor(psum[i], 32);
  }
  if (lq == 0) {
    atomicAdd(&rsum[(size_t)(b * Hh + w) * Nn + n0 + lm], psum[0]);
    atomicAdd(&rsum[(size_t)(b * Hh + w) * Nn + n0 + 16 + lm], psum[1]);
  }
}

// ---------------- kB: mix + stats + S@V (single-z, no spill) ---------------
// grid (b=8, nt=64); block 512 = 8 waves; wave w = group g.
__global__ __launch_bounds__(512, 2) void k_mixsv(const unsigned short* __restrict__ Sg,
                                                  const unsigned short* __restrict__ vT,
                                                  const float* __restrict__ rsum,
                                                  const float* __restrict__ conv_w,
                                                  float* __restrict__ O1,
                                                  float* __restrict__ stats) {
  __shared__ unsigned short sU[8][16][68];  // 17,408 B
  __shared__ float sRed[8][16];
  const int b = blockIdx.x;  // b fastest -> XCD-pinned vT slice in L2
  const int n0 = blockIdx.y * 16;
  const int t = threadIdx.x;
  const int w = t >> 6, l = t & 63;
  const int lm = l & 15, lq = l >> 4;
  const int mxn = t >> 5, mxm = (t & 31) * 2;
  float cw[64];
#pragma unroll
  for (int i = 0; i < 64; i++) cw[i] = conv_w[i];  // uniform -> SGPRs
  float rv[8];
#pragma unroll
  for (int h = 0; h < 8; h++) rv[h] = 1.0f / rsum[(size_t)(b * Hh + h) * Nn + n0 + mxn];
  const unsigned short* sNp = Sg + ((size_t)(b * Nn + n0 + mxn) << 13);  // row base *8192
  f32x4 oacc[4] = {};
  float su[8] = {}, su2[8] = {};
  uint4 c0, c1;
  {
    const unsigned short* p = sNp + (mxm << 3);
    c0 = *(const uint4*)p;
    c1 = *(const uint4*)(p + 8);
  }
  for (int it = 0; it < 16; it++) {
    uint4 nx0, nx1;
    if (it < 15) {  // shallow prefetch (2 uint4 live extra — no spill at cap 256)
      const unsigned short* p = sNp + ((size_t)((it + 1) * 64 + mxm) << 3);
      nx0 = *(const uint4*)p;
      nx1 = *(const uint4*)(p + 8);
    }
    {  // mix: 2 m-positions x 8 heads from c0/c1
      const unsigned* pe = (const unsigned*)&c0;  // m even, heads 0..7
      const unsigned* po = (const unsigned*)&c1;  // m odd,  heads 0..7
      float sx[8], sy[8];
#pragma unroll
      for (int hp = 0; hp < 4; hp++) {
        sx[2 * hp] = h2f((unsigned short)(pe[hp] & 0xffff)) * rv[2 * hp];
        sx[2 * hp + 1] = h2f((unsigned short)(pe[hp] >> 16)) * rv[2 * hp + 1];
        sy[2 * hp] = h2f((unsigned short)(po[hp] & 0xffff)) * rv[2 * hp];
        sy[2 * hp + 1] = h2f((unsigned short)(po[hp] >> 16)) * rv[2 * hp + 1];
      }
#pragma unroll
      for (int g = 0; g < 8; g++) {
        float u0 = 0.f, u1 = 0.f;
#pragma unroll
        for (int h = 0; h < 8; h++) {
          u0 += cw[g * 8 + h] * sx[h];
          u1 += cw[g * 8 + h] * sy[h];
        }
        su[g] += u0 + u1;
        su2[g] += u0 * u0 + u1 * u1;
        *(unsigned*)&sU[g][mxn][mxm] = (unsigned)f2h(u0) | ((unsigned)f2h(u1) << 16);
      }
    }
    __syncthreads();  // sU ready
    {  // S@V for group w: A = sU[w], B = vT direct from global (L2-hot)
      f16x8 uf0 = *(const f16x8*)&sU[w][lm][lq * 8];
      f16x8 uf1 = *(const f16x8*)&sU[w][lm][32 + lq * 8];
#pragma unroll
      for (int j = 0; j < 4; j++) {
        const unsigned short* vp =
            vT + (((size_t)(b * Hh + w) * DH + 16 * j + lm) << 10) + it * 64 + lq * 8;
        f16x8 v0 = *(const f16x8*)vp;
        f16x8 v1 = *(const f16x8*)(vp + 32);
        oacc[j] = MFMA16(uf0, v0, oacc[j]);
        oacc[j] = MFMA16(uf1, v1, oacc[j]);
      }
    }
    __syncthreads();  // PV readers done before next mix overwrites sU
    if (it < 15) {
      c0 = nx0;
      c1 = nx1;
    }
  }
#pragma unroll
  for (int j = 0; j < 4; j++)
#pragma unroll
    for (int r = 0; r < 4; r++)
      O1[((size_t)(b * Hh + w) * Nn + n0 + lq * 4 + r) * DH + 16 * j + lm] = oacc[j][r];
#pragma unroll
  for (int g = 0; g < 8; g++) {
    float a = su[g], q = su2[g];
    for (int off = 32; off; off >>= 1) {
      a += __shfl_down(a, off);
      q += __shfl_down(q, off);
    }
    if (l == 0) {
      sRed[w][g] = a;
      sRed[w][8 + g] = q;
    }
  }
  __syncthreads();
  if (t < 16) {
    float s = 0.f;
#pragma unroll
    for (int ww = 0; ww < 8; ww++) s += sRed[ww][t];
    atomicAdd(&stats[t], s);
  }
}

// ---------------- K3: alpha/const ------------------------------------------
__global__ void k_alpha(const float* __restrict__ stats, const float* __restrict__ bn_gamma,
                        const float* __restrict__ bn_beta, float* __restrict__ ac) {
  const int g = threadIdx.x;
  if (g < 8) {
    const float cnt = (float)Bz * (float)Nn * (float)Nn;
    float Eu = stats[g] / cnt;
    float Eu2 = stats[8 + g] / cnt;
    float inv = rsqrtf(Eu2 - Eu * Eu + BN_EPS);
    float alpha = bn_gamma[g] * inv;
    ac[g] = alpha;
    ac[8 + g] = bn_beta[g] - Eu * alpha;
  }
}

// ---------------- k_o1aff: O1hf = fp16(alpha*O1 + c*vsum) ------------------
__global__ __launch_bounds__(256) void k_o1aff(const float* __restrict__ O1,
                                               const float* __restrict__ vsum,
                                               const float* __restrict__ ac,
                                               unsigned short* __restrict__ O1BF) {
  const size_t i4 = ((size_t)blockIdx.x * 256 + threadIdx.x) * 4;
  const int bg = (int)(i4 >> 16);
  const int g = bg & 7;
  const int d = (int)(i4 & 63);
  float4 a = *(const float4*)(O1 + i4);
  float4 v = *(const float4*)(vsum + (size_t)bg * DH + d);
  const float al = ac[g], cc = ac[8 + g];
  unsigned short o[4] = {f2h(al * a.x + cc * v.x), f2h(al * a.y + cc * v.y),
                         f2h(al * a.z + cc * v.z), f2h(al * a.w + cc * v.w)};
  *(uint2*)(O1BF + i4) = *(uint2*)o;
}

// ---------------- K4: out = O1hf @ w_out + b_out (fp16 MFMA) ---------------
__global__ __launch_bounds__(256) void k_out(const unsigned short* __restrict__ O1BF,
                                             const unsigned short* __restrict__ WOT,
                                             const float* __restrict__ bout,
                                             float* __restrict__ out) {
  __shared__ unsigned short sA[128][40];
  __shared__ unsigned short sB[128][40];
  const int t = threadIdx.x;
  const int col0 = blockIdx.x * 128, row0 = blockIdx.y * 128;
  const int l = t & 63, w = t >> 6;
  const int wm = (w & 1) * 64, wn = (w >> 1) * 64;
  const int lm = l & 15, lq = l >> 4;
  const int srow = t >> 1, skc = (t & 1) * 16;
  const int b = row0 >> 10;
  const int nn = (row0 + srow) & 1023;
  f32x4 acc[4][4] = {};
  for (int k0 = 0; k0 < INNER; k0 += 32) {
    {
      const int k = k0 + skc;
      const int g = k >> 6, dd = k & 63;
      const unsigned short* src = O1BF + ((size_t)(b * Hh + g) * Nn + nn) * DH + dd;
      *(uint4*)&sA[srow][skc] = *(const uint4*)src;
      *(uint4*)&sA[srow][skc + 8] = *(const uint4*)(src + 8);
    }
    {
      const unsigned short* srcB = WOT + (size_t)(col0 + srow) * INNER + k0 + skc;
      *(uint4*)&sB[srow][skc] = *(const uint4*)srcB;
      *(uint4*)&sB[srow][skc + 8] = *(const uint4*)(srcB + 8);
    }
    __syncthreads();
    f16x8 af[4], bfr[4];
#pragma unroll
    for (int i = 0; i < 4; i++) af[i] = *(const f16x8*)&sA[wm + 16 * i + lm][lq * 8];
#pragma unroll
    for (int j = 0; j < 4; j++) bfr[j] = *(const f16x8*)&sB[wn + 16 * j + lm][lq * 8];
#pragma unroll
    for (int i = 0; i < 4; i++)
#pragma unroll
      for (int j = 0; j < 4; j++) acc[i][j] = MFMA16(af[i], bfr[j], acc[i][j]);
    __syncthreads();
  }
#pragma unroll
  for (int j = 0; j < 4; j++) {
    const int col = col0 + wn + 16 * j + lm;
    const float bo = bout[col];
#pragma unroll
    for (int i = 0; i < 4; i++) {
      const int rbase = row0 + wm + 16 * i + lq * 4;
#pragma unroll
      for (int r = 0; r < 4; r++) out[(size_t)(rbase + r) * Dd + col] = acc[i][j][r] + bo;
    }
  }
}

extern "C" void kernel_launch(void* const* d_in, const int* in_sizes, int n_in,
                              void* d_out, int out_size, void* d_ws, size_t ws_size,
                              hipStream_t stream) {
  const float* x = (const float*)d_in[0];
  const float* w_qkv = (const float*)d_in[1];
  const float* conv_w = (const float*)d_in[2];
  // d_in[3] = conv_b : cancels in train-mode BN.
  const float* bn_gamma = (const float*)d_in[4];
  const float* bn_beta = (const float*)d_in[5];
  const float* w_out = (const float*)d_in[6];
  const float* b_out = (const float*)d_in[7];
  char* ws = (char*)d_ws;
  unsigned short* XB = (unsigned short*)(ws + WB_XB);
  unsigned short* QKV = (unsigned short*)(ws + WB_QKV);
  unsigned short* VT = (unsigned short*)(ws + WB_VT);
  unsigned short* SG = (unsigned short*)(ws + WB_SG);
  unsigned short* WQT = (unsigned short*)(ws + WB_WQT);
  unsigned short* WOT = (unsigned short*)(ws + WB_WOT);
  float* O1 = (float*)(ws + WB_O1);
  unsigned short* O1BF = (unsigned short*)(ws + WB_O1BF);
  float* RSUM = (float*)(ws + WB_RSUM);
  float* VSUM = (float*)(ws + WB_VSUM);
  float* STATS = (float*)(ws + WB_STATS);
  float* AC = (float*)(ws + WB_AC);

  hipMemsetAsync(STATS, 0, 64, stream);
  hipMemsetAsync(RSUM, 0, 262144, stream);
  k_xbf<<<2048, 256, 0, stream>>>(x, XB);
  k_transpose<<<dim3(48, 16), 256, 0, stream>>>(w_qkv, WQT, 512, 1536);
  k_transpose<<<dim3(16, 16), 256, 0, stream>>>(w_out, WOT, 512, 512);
  k_qkv<<<dim3(12, 64), 256, 34816, stream>>>(XB, WQT, QKV, VT);
  k_vsum<<<64, 256, 0, stream>>>(VT, VSUM);
  k_sgen<<<dim3(8, 32, 2), 512, 0, stream>>>(QKV, SG, RSUM);
  k_mixsv<<<dim3(8, 64), 512, 0, stream>>>(SG, VT, RSUM, conv_w, O1, STATS);
  k_alpha<<<1, 64, 0, stream>>>(STATS, bn_gamma, bn_beta, AC);
  k_o1aff<<<4096, 256, 0, stream>>>(O1, VSUM, AC, O1BF);
  k_out<<<dim3(4, 64), 256, 0, stream>>>(O1BF, WOT, b_out, (float*)d_out);
}